// Round 8
// baseline (91.803 us; speedup 1.0000x reference)
//
#include <hip/hip_runtime.h>
#include <hip/hip_bf16.h>

#define B 16
#define S 2048
#define VOCAB 32000
#define D_EMB 256
#define D_MODEL 512
#define LN_EPS 1e-5f

using bf16x8 = __attribute__((ext_vector_type(8))) short;
using f32x4  = __attribute__((ext_vector_type(4))) float;

static __device__ __forceinline__ unsigned short f2bf(float f) {
    __hip_bfloat16 h = __float2bfloat16(f);   // RNE
    return *reinterpret_cast<unsigned short*>(&h);
}

static __device__ __forceinline__ bf16x8 pack8(f32x4 v0, f32x4 v1) {
    union { unsigned short us[8]; bf16x8 v; } pk;
    pk.us[0] = f2bf(v0.x); pk.us[1] = f2bf(v0.y);
    pk.us[2] = f2bf(v0.z); pk.us[3] = f2bf(v0.w);
    pk.us[4] = f2bf(v1.x); pk.us[5] = f2bf(v1.y);
    pk.us[6] = f2bf(v1.z); pk.us[7] = f2bf(v1.w);
    return pk.v;
}

// ---------------------------------------------------------------------------
// Kernel A (MFMA) — EXACT R5 form. Launched TWICE this round (idempotent)
// as an attribution probe: total - 68.7 = standalone A duration.
// ---------------------------------------------------------------------------
__global__ __launch_bounds__(256) void wk_mfma(
    const float* __restrict__ Wb,
    const float* __restrict__ king_table,
    const int* __restrict__ king_id,
    unsigned short* __restrict__ Wk)
{
    const int t    = threadIdx.x;
    const int lane = t & 63;
    const int wave = t >> 6;
    const int lr   = lane & 15;     // b index (B-frag col) / row index (A-frag)
    const int kg   = lane >> 4;     // k-group

    const int kid = king_id[lr];
    const float* kp = king_table + (size_t)kid * D_EMB + kg * 8;
    bf16x8 bemb[8];
#pragma unroll
    for (int step = 0; step < 8; ++step) {
        f32x4 v0 = *(const f32x4*)(kp + step * 32);
        f32x4 v1 = *(const f32x4*)(kp + step * 32 + 4);
        bemb[step] = pack8(v0, v1);
    }

    const int rbase = (blockIdx.x * 4 + wave) * 64;

#pragma unroll
    for (int mf = 0; mf < 4; ++mf) {
        const float* arow = Wb + (size_t)(rbase + mf * 16 + lr) * D_EMB + kg * 8;
        f32x4 acc = {};
#pragma unroll
        for (int step = 0; step < 8; ++step) {
            f32x4 v0 = *(const f32x4*)(arow + step * 32);
            f32x4 v1 = *(const f32x4*)(arow + step * 32 + 4);
            acc = __builtin_amdgcn_mfma_f32_16x16x32_bf16(
                pack8(v0, v1), bemb[step], acc, 0, 0, 0);
        }
        union { unsigned short us[4]; uint2 q; } st;
        st.us[0] = f2bf(acc[0]); st.us[1] = f2bf(acc[1]);
        st.us[2] = f2bf(acc[2]); st.us[3] = f2bf(acc[3]);
        *(uint2*)(Wk + (size_t)lr * (D_MODEL * D_EMB) + rbase + mf * 16 + kg * 4) = st.q;
    }
}

// ---------------------------------------------------------------------------
// Kernel B (MFMA) — EXACT R5 form: tile 64 s x 512 m, tok staged once in
// LDS, Wk B-fragments direct from global (L2), no K-loop barriers.
// ---------------------------------------------------------------------------
#define TSB 64

__global__ __launch_bounds__(512) void gemm_ln_mfma(
    const int* __restrict__ seq,
    const int* __restrict__ king_id,
    const float* __restrict__ token_tables,
    const unsigned short* __restrict__ Wk,
    const float* __restrict__ bb,
    const float* __restrict__ gamma,
    const float* __restrict__ beta,
    float* __restrict__ out)
{
    __shared__ unsigned short tokL[TSB][264];   // 64 x (256+8 pad) bf16 = 33 KB
    __shared__ float red_sum[8][TSB];
    __shared__ float red_sq[8][TSB];
    __shared__ float stats[2][TSB];             // [0]=mean, [1]=rstd

    const int b    = blockIdx.y;
    const int s0   = blockIdx.x * TSB;
    const int t    = threadIdx.x;
    const int lane = t & 63;
    const int wave = t >> 6;
    const int lr   = lane & 15;     // frag row/col index
    const int kg   = lane >> 4;     // k-group (0..3)

    const int kb = king_id[b];
    const float* ttab = token_tables + (size_t)kb * VOCAB * D_EMB;

    // ---- stage gathered tok tile: fp32 global -> bf16 LDS ----
    {
        int row = t >> 3;            // 0..63
        int ck  = (t & 7) * 32;      // k chunk start (32 floats)
        int tokidx = seq[b * S + s0 + row];
        const float4* src = (const float4*)(ttab + (size_t)tokidx * D_EMB + ck);
#pragma unroll
        for (int u = 0; u < 4; ++u) {
            float4 v0 = src[u * 2 + 0];
            float4 v1 = src[u * 2 + 1];
            union { unsigned short us[8]; uint4 q; } pk;
            pk.us[0] = f2bf(v0.x); pk.us[1] = f2bf(v0.y);
            pk.us[2] = f2bf(v0.z); pk.us[3] = f2bf(v0.w);
            pk.us[4] = f2bf(v1.x); pk.us[5] = f2bf(v1.y);
            pk.us[6] = f2bf(v1.z); pk.us[7] = f2bf(v1.w);
            *(uint4*)&tokL[row][ck + u * 8] = pk.q;
        }
    }
    __syncthreads();

    // ---- fragment pointers ----
    const int m0 = wave * 64;                  // wave's m-slice base
    const uint4* aptr[4];
    const uint4* bptr[4];
#pragma unroll
    for (int mf = 0; mf < 4; ++mf)
        aptr[mf] = (const uint4*)&tokL[mf * 16 + lr][kg * 8];
#pragma unroll
    for (int nf = 0; nf < 4; ++nf) {
        int col = m0 + nf * 16 + lr;
        bptr[nf] = (const uint4*)(Wk + ((size_t)(b * D_MODEL + col)) * D_EMB + kg * 8);
    }

    f32x4 acc[4][4] = {};

    // ---- K loop: 8 steps of K=32, fully unrolled ----
#pragma unroll
    for (int step = 0; step < 8; ++step) {
        bf16x8 af[4], bfr[4];
#pragma unroll
        for (int mf = 0; mf < 4; ++mf) {
            uint4 q = aptr[mf][step * 4];
            af[mf] = __builtin_bit_cast(bf16x8, q);
        }
#pragma unroll
        for (int nf = 0; nf < 4; ++nf) {
            uint4 q = bptr[nf][step * 4];
            bfr[nf] = __builtin_bit_cast(bf16x8, q);
        }
#pragma unroll
        for (int mf = 0; mf < 4; ++mf)
#pragma unroll
            for (int nf = 0; nf < 4; ++nf)
                acc[mf][nf] = __builtin_amdgcn_mfma_f32_16x16x32_bf16(
                    af[mf], bfr[nf], acc[mf][nf], 0, 0, 0);
    }

    // ---- epilogue: bias, block-wide LN stats ----
    float bbv[4], gv[4], bv[4];
#pragma unroll
    for (int nf = 0; nf < 4; ++nf) {
        int col = m0 + nf * 16 + lr;
        bbv[nf] = bb[col];
        gv[nf]  = gamma[col];
        bv[nf]  = beta[col];
    }

#pragma unroll
    for (int mf = 0; mf < 4; ++mf) {
#pragma unroll
        for (int r = 0; r < 4; ++r) {
            float sum = 0.0f, sq = 0.0f;
#pragma unroll
            for (int nf = 0; nf < 4; ++nf) {
                float v = acc[mf][nf][r] + bbv[nf];
                acc[mf][nf][r] = v;
                sum += v;
                sq  += v * v;
            }
#pragma unroll
            for (int off = 1; off < 16; off <<= 1) {
                sum += __shfl_xor(sum, off);
                sq  += __shfl_xor(sq, off);
            }
            if (lr == 0) {
                int row = mf * 16 + kg * 4 + r;
                red_sum[wave][row] = sum;
                red_sq[wave][row]  = sq;
            }
        }
    }
    __syncthreads();

    if (t < TSB) {
        float s = 0.0f, q = 0.0f;
#pragma unroll
        for (int w = 0; w < 8; ++w) { s += red_sum[w][t]; q += red_sq[w][t]; }
        float mean = s * (1.0f / D_MODEL);
        float var  = q * (1.0f / D_MODEL) - mean * mean;
        stats[0][t] = mean;
        stats[1][t] = rsqrtf(var + LN_EPS);
    }
    __syncthreads();

    // ---- normalize + store ----
#pragma unroll
    for (int mf = 0; mf < 4; ++mf) {
#pragma unroll
        for (int r = 0; r < 4; ++r) {
            int row = mf * 16 + kg * 4 + r;
            float mean = stats[0][row];
            float rstd = stats[1][row];
            float* op = out + ((size_t)b * S + s0 + row) * D_MODEL + m0 + lr;
#pragma unroll
            for (int nf = 0; nf < 4; ++nf)
                op[nf * 16] = (acc[mf][nf][r] - mean) * rstd * gv[nf] + bv[nf];
        }
    }
}

// ---------------------------------------------------------------------------
extern "C" void kernel_launch(void* const* d_in, const int* in_sizes, int n_in,
                              void* d_out, int out_size, void* d_ws, size_t ws_size,
                              hipStream_t stream)
{
    const int*   seq          = (const int*)d_in[0];
    const int*   king_id      = (const int*)d_in[1];
    const float* token_tables = (const float*)d_in[2];
    const float* Wb           = (const float*)d_in[3];
    const float* bb           = (const float*)d_in[4];
    const float* king_table   = (const float*)d_in[5];
    const float* gamma        = (const float*)d_in[6];
    const float* beta         = (const float*)d_in[7];
    float* out = (float*)d_out;

    unsigned short* Wk = (unsigned short*)d_ws;   // B*D_MODEL*D_EMB bf16 = 4 MB

    // ATTRIBUTION PROBE: A launched twice (idempotent). total - 68.7 = A.
    wk_mfma<<<dim3((D_MODEL * D_EMB) / 256), dim3(256), 0, stream>>>(
        Wb, king_table, king_id, Wk);
    wk_mfma<<<dim3((D_MODEL * D_EMB) / 256), dim3(256), 0, stream>>>(
        Wb, king_table, king_id, Wk);
    gemm_ln_mfma<<<dim3(S / TSB, B), dim3(512), 0, stream>>>(
        seq, king_id, token_tables, Wk, bb, gamma, beta, out);
}

// Round 9
// 63.267 us; speedup vs baseline: 1.4510x; 1.4510x over previous
//
#include <hip/hip_runtime.h>
#include <hip/hip_bf16.h>

#define B 16
#define S 2048
#define VOCAB 32000
#define D_EMB 256
#define D_MODEL 512
#define LN_EPS 1e-5f

using bf16x8 = __attribute__((ext_vector_type(8))) short;
using f32x4  = __attribute__((ext_vector_type(4))) float;

static __device__ __forceinline__ unsigned short f2bf(float f) {
    __hip_bfloat16 h = __float2bfloat16(f);   // RNE
    return *reinterpret_cast<unsigned short*>(&h);
}

static __device__ __forceinline__ bf16x8 pack8(f32x4 v0, f32x4 v1) {
    union { unsigned short us[8]; bf16x8 v; } pk;
    pk.us[0] = f2bf(v0.x); pk.us[1] = f2bf(v0.y);
    pk.us[2] = f2bf(v0.z); pk.us[3] = f2bf(v0.w);
    pk.us[4] = f2bf(v1.x); pk.us[5] = f2bf(v1.y);
    pk.us[6] = f2bf(v1.z); pk.us[7] = f2bf(v1.w);
    return pk.v;
}

// ---------------------------------------------------------------------------
// Kernel A (MFMA) — EXACT R5 form (measured: 23.1 µs, ~ its 21 µs Wb floor).
// ---------------------------------------------------------------------------
__global__ __launch_bounds__(256) void wk_mfma(
    const float* __restrict__ Wb,
    const float* __restrict__ king_table,
    const int* __restrict__ king_id,
    unsigned short* __restrict__ Wk)
{
    const int t    = threadIdx.x;
    const int lane = t & 63;
    const int wave = t >> 6;
    const int lr   = lane & 15;     // b index (B-frag col) / row index (A-frag)
    const int kg   = lane >> 4;     // k-group

    const int kid = king_id[lr];
    const float* kp = king_table + (size_t)kid * D_EMB + kg * 8;
    bf16x8 bemb[8];
#pragma unroll
    for (int step = 0; step < 8; ++step) {
        f32x4 v0 = *(const f32x4*)(kp + step * 32);
        f32x4 v1 = *(const f32x4*)(kp + step * 32 + 4);
        bemb[step] = pack8(v0, v1);
    }

    const int rbase = (blockIdx.x * 4 + wave) * 64;

#pragma unroll
    for (int mf = 0; mf < 4; ++mf) {
        const float* arow = Wb + (size_t)(rbase + mf * 16 + lr) * D_EMB + kg * 8;
        f32x4 acc = {};
#pragma unroll
        for (int step = 0; step < 8; ++step) {
            f32x4 v0 = *(const f32x4*)(arow + step * 32);
            f32x4 v1 = *(const f32x4*)(arow + step * 32 + 4);
            acc = __builtin_amdgcn_mfma_f32_16x16x32_bf16(
                pack8(v0, v1), bemb[step], acc, 0, 0, 0);
        }
        union { unsigned short us[4]; uint2 q; } st;
        st.us[0] = f2bf(acc[0]); st.us[1] = f2bf(acc[1]);
        st.us[2] = f2bf(acc[2]); st.us[3] = f2bf(acc[3]);
        *(uint2*)(Wk + (size_t)lr * (D_MODEL * D_EMB) + rbase + mf * 16 + kg * 4) = st.q;
    }
}

// ---------------------------------------------------------------------------
// Kernel B (MFMA) — R5 form + __launch_bounds__(512, 4):
// 4 waves/EU -> 2 blocks/CU (16 waves/CU), VGPR capped at 128 so the
// stage phase of one block overlaps the MFMA/Wk-load phase of the other.
// Everything else byte-identical to the measured 68.7 µs config.
// ---------------------------------------------------------------------------
#define TSB 64

__global__ __launch_bounds__(512, 4) void gemm_ln_mfma(
    const int* __restrict__ seq,
    const int* __restrict__ king_id,
    const float* __restrict__ token_tables,
    const unsigned short* __restrict__ Wk,
    const float* __restrict__ bb,
    const float* __restrict__ gamma,
    const float* __restrict__ beta,
    float* __restrict__ out)
{
    __shared__ unsigned short tokL[TSB][264];   // 64 x (256+8 pad) bf16 = 33 KB
    __shared__ float red_sum[8][TSB];
    __shared__ float red_sq[8][TSB];
    __shared__ float stats[2][TSB];             // [0]=mean, [1]=rstd

    const int b    = blockIdx.y;
    const int s0   = blockIdx.x * TSB;
    const int t    = threadIdx.x;
    const int lane = t & 63;
    const int wave = t >> 6;
    const int lr   = lane & 15;     // frag row/col index
    const int kg   = lane >> 4;     // k-group (0..3)

    const int kb = king_id[b];
    const float* ttab = token_tables + (size_t)kb * VOCAB * D_EMB;

    // ---- stage gathered tok tile: fp32 global -> bf16 LDS ----
    {
        int row = t >> 3;            // 0..63
        int ck  = (t & 7) * 32;      // k chunk start (32 floats)
        int tokidx = seq[b * S + s0 + row];
        const float4* src = (const float4*)(ttab + (size_t)tokidx * D_EMB + ck);
#pragma unroll
        for (int u = 0; u < 4; ++u) {
            float4 v0 = src[u * 2 + 0];
            float4 v1 = src[u * 2 + 1];
            union { unsigned short us[8]; uint4 q; } pk;
            pk.us[0] = f2bf(v0.x); pk.us[1] = f2bf(v0.y);
            pk.us[2] = f2bf(v0.z); pk.us[3] = f2bf(v0.w);
            pk.us[4] = f2bf(v1.x); pk.us[5] = f2bf(v1.y);
            pk.us[6] = f2bf(v1.z); pk.us[7] = f2bf(v1.w);
            *(uint4*)&tokL[row][ck + u * 8] = pk.q;
        }
    }
    __syncthreads();

    // ---- fragment pointers ----
    const int m0 = wave * 64;                  // wave's m-slice base
    const uint4* aptr[4];
    const uint4* bptr[4];
#pragma unroll
    for (int mf = 0; mf < 4; ++mf)
        aptr[mf] = (const uint4*)&tokL[mf * 16 + lr][kg * 8];
#pragma unroll
    for (int nf = 0; nf < 4; ++nf) {
        int col = m0 + nf * 16 + lr;
        bptr[nf] = (const uint4*)(Wk + ((size_t)(b * D_MODEL + col)) * D_EMB + kg * 8);
    }

    f32x4 acc[4][4] = {};

    // ---- K loop: 8 steps of K=32, fully unrolled ----
#pragma unroll
    for (int step = 0; step < 8; ++step) {
        bf16x8 af[4], bfr[4];
#pragma unroll
        for (int mf = 0; mf < 4; ++mf) {
            uint4 q = aptr[mf][step * 4];
            af[mf] = __builtin_bit_cast(bf16x8, q);
        }
#pragma unroll
        for (int nf = 0; nf < 4; ++nf) {
            uint4 q = bptr[nf][step * 4];
            bfr[nf] = __builtin_bit_cast(bf16x8, q);
        }
#pragma unroll
        for (int mf = 0; mf < 4; ++mf)
#pragma unroll
            for (int nf = 0; nf < 4; ++nf)
                acc[mf][nf] = __builtin_amdgcn_mfma_f32_16x16x32_bf16(
                    af[mf], bfr[nf], acc[mf][nf], 0, 0, 0);
    }

    // ---- epilogue: bias, block-wide LN stats ----
    float bbv[4], gv[4], bv[4];
#pragma unroll
    for (int nf = 0; nf < 4; ++nf) {
        int col = m0 + nf * 16 + lr;
        bbv[nf] = bb[col];
        gv[nf]  = gamma[col];
        bv[nf]  = beta[col];
    }

#pragma unroll
    for (int mf = 0; mf < 4; ++mf) {
#pragma unroll
        for (int r = 0; r < 4; ++r) {
            float sum = 0.0f, sq = 0.0f;
#pragma unroll
            for (int nf = 0; nf < 4; ++nf) {
                float v = acc[mf][nf][r] + bbv[nf];
                acc[mf][nf][r] = v;
                sum += v;
                sq  += v * v;
            }
#pragma unroll
            for (int off = 1; off < 16; off <<= 1) {
                sum += __shfl_xor(sum, off);
                sq  += __shfl_xor(sq, off);
            }
            if (lr == 0) {
                int row = mf * 16 + kg * 4 + r;
                red_sum[wave][row] = sum;
                red_sq[wave][row]  = sq;
            }
        }
    }
    __syncthreads();

    if (t < TSB) {
        float s = 0.0f, q = 0.0f;
#pragma unroll
        for (int w = 0; w < 8; ++w) { s += red_sum[w][t]; q += red_sq[w][t]; }
        float mean = s * (1.0f / D_MODEL);
        float var  = q * (1.0f / D_MODEL) - mean * mean;
        stats[0][t] = mean;
        stats[1][t] = rsqrtf(var + LN_EPS);
    }
    __syncthreads();

    // ---- normalize + store ----
#pragma unroll
    for (int mf = 0; mf < 4; ++mf) {
#pragma unroll
        for (int r = 0; r < 4; ++r) {
            int row = mf * 16 + kg * 4 + r;
            float mean = stats[0][row];
            float rstd = stats[1][row];
            float* op = out + ((size_t)b * S + s0 + row) * D_MODEL + m0 + lr;
#pragma unroll
            for (int nf = 0; nf < 4; ++nf)
                op[nf * 16] = (acc[mf][nf][r] - mean) * rstd * gv[nf] + bv[nf];
        }
    }
}

// ---------------------------------------------------------------------------
extern "C" void kernel_launch(void* const* d_in, const int* in_sizes, int n_in,
                              void* d_out, int out_size, void* d_ws, size_t ws_size,
                              hipStream_t stream)
{
    const int*   seq          = (const int*)d_in[0];
    const int*   king_id      = (const int*)d_in[1];
    const float* token_tables = (const float*)d_in[2];
    const float* Wb           = (const float*)d_in[3];
    const float* bb           = (const float*)d_in[4];
    const float* king_table   = (const float*)d_in[5];
    const float* gamma        = (const float*)d_in[6];
    const float* beta         = (const float*)d_in[7];
    float* out = (float*)d_out;

    unsigned short* Wk = (unsigned short*)d_ws;   // B*D_MODEL*D_EMB bf16 = 4 MB

    wk_mfma<<<dim3((D_MODEL * D_EMB) / 256), dim3(256), 0, stream>>>(
        Wb, king_table, king_id, Wk);
    gemm_ln_mfma<<<dim3(S / TSB, B), dim3(512), 0, stream>>>(
        seq, king_id, token_tables, Wk, bb, gamma, beta, out);
}

// Round 10
// 59.998 us; speedup vs baseline: 1.5301x; 1.0545x over previous
//
#include <hip/hip_runtime.h>
#include <hip/hip_bf16.h>

#define B 16
#define S 2048
#define VOCAB 32000
#define D_EMB 256
#define D_MODEL 512
#define LN_EPS 1e-5f

using bf16x8 = __attribute__((ext_vector_type(8))) short;
using f32x4  = __attribute__((ext_vector_type(4))) float;

static __device__ __forceinline__ unsigned short f2bf(float f) {
    __hip_bfloat16 h = __float2bfloat16(f);   // RNE
    return *reinterpret_cast<unsigned short*>(&h);
}

static __device__ __forceinline__ bf16x8 pack8(f32x4 v0, f32x4 v1) {
    union { unsigned short us[8]; bf16x8 v; } pk;
    pk.us[0] = f2bf(v0.x); pk.us[1] = f2bf(v0.y);
    pk.us[2] = f2bf(v0.z); pk.us[3] = f2bf(v0.w);
    pk.us[4] = f2bf(v1.x); pk.us[5] = f2bf(v1.y);
    pk.us[6] = f2bf(v1.z); pk.us[7] = f2bf(v1.w);
    return pk.v;
}

// ---------------------------------------------------------------------------
// Kernel A (MFMA) — EXACT R5 form (measured: 23.1 µs ≈ its 21 µs Wb floor).
// ---------------------------------------------------------------------------
__global__ __launch_bounds__(256) void wk_mfma(
    const float* __restrict__ Wb,
    const float* __restrict__ king_table,
    const int* __restrict__ king_id,
    unsigned short* __restrict__ Wk)
{
    const int t    = threadIdx.x;
    const int lane = t & 63;
    const int wave = t >> 6;
    const int lr   = lane & 15;     // b index (B-frag col) / row index (A-frag)
    const int kg   = lane >> 4;     // k-group

    const int kid = king_id[lr];
    const float* kp = king_table + (size_t)kid * D_EMB + kg * 8;
    bf16x8 bemb[8];
#pragma unroll
    for (int step = 0; step < 8; ++step) {
        f32x4 v0 = *(const f32x4*)(kp + step * 32);
        f32x4 v1 = *(const f32x4*)(kp + step * 32 + 4);
        bemb[step] = pack8(v0, v1);
    }

    const int rbase = (blockIdx.x * 4 + wave) * 64;

#pragma unroll
    for (int mf = 0; mf < 4; ++mf) {
        const float* arow = Wb + (size_t)(rbase + mf * 16 + lr) * D_EMB + kg * 8;
        f32x4 acc = {};
#pragma unroll
        for (int step = 0; step < 8; ++step) {
            f32x4 v0 = *(const f32x4*)(arow + step * 32);
            f32x4 v1 = *(const f32x4*)(arow + step * 32 + 4);
            acc = __builtin_amdgcn_mfma_f32_16x16x32_bf16(
                pack8(v0, v1), bemb[step], acc, 0, 0, 0);
        }
        union { unsigned short us[4]; uint2 q; } st;
        st.us[0] = f2bf(acc[0]); st.us[1] = f2bf(acc[1]);
        st.us[2] = f2bf(acc[2]); st.us[3] = f2bf(acc[3]);
        *(uint2*)(Wk + (size_t)lr * (D_MODEL * D_EMB) + rbase + mf * 16 + kg * 4) = st.q;
    }
}

// ---------------------------------------------------------------------------
// Kernel B (MFMA) — R9 form + K-split staging pipeline (T14 issue-early):
//   stage tok k[0,128) -> barrier -> issue k[128,256) loads ->
//   compute K-steps 0-3 -> convert+ds_write held regs -> barrier ->
//   compute K-steps 4-7.
// First MFMA starts after HALF the gather; second gather half overlaps
// steps 0-3's MFMA + Wk L2 loads. No Wk traffic duplication (K-split).
// ---------------------------------------------------------------------------
#define TSB 64

__global__ __launch_bounds__(512, 4) void gemm_ln_mfma(
    const int* __restrict__ seq,
    const int* __restrict__ king_id,
    const float* __restrict__ token_tables,
    const unsigned short* __restrict__ Wk,
    const float* __restrict__ bb,
    const float* __restrict__ gamma,
    const float* __restrict__ beta,
    float* __restrict__ out)
{
    __shared__ unsigned short tokL[TSB][264];   // 64 x (256+8 pad) bf16 = 33 KB
    __shared__ float red_sum[8][TSB];
    __shared__ float red_sq[8][TSB];
    __shared__ float stats[2][TSB];             // [0]=mean, [1]=rstd

    const int b    = blockIdx.y;
    const int s0   = blockIdx.x * TSB;
    const int t    = threadIdx.x;
    const int lane = t & 63;
    const int wave = t >> 6;
    const int lr   = lane & 15;     // frag row/col index
    const int kg   = lane >> 4;     // k-group (0..3)

    const int kb = king_id[b];
    const float* ttab = token_tables + (size_t)kb * VOCAB * D_EMB;

    // staging geometry: thread t covers row = t>>3, k-chunk (t&7)*16 within
    // each 128-col half (16 floats = 4 dwordx4 per half).
    const int srow = t >> 3;
    const int sck  = (t & 7) * 16;
    const int tokidx = seq[b * S + s0 + srow];
    const float* srcrow = ttab + (size_t)tokidx * D_EMB + sck;

    // ---- phase 0: stage k-half 0 ([0,128)) ----
    {
        f32x4 v0 = *(const f32x4*)(srcrow + 0);
        f32x4 v1 = *(const f32x4*)(srcrow + 4);
        f32x4 v2 = *(const f32x4*)(srcrow + 8);
        f32x4 v3 = *(const f32x4*)(srcrow + 12);
        *(bf16x8*)&tokL[srow][sck]     = pack8(v0, v1);
        *(bf16x8*)&tokL[srow][sck + 8] = pack8(v2, v3);
    }
    __syncthreads();

    // ---- issue k-half 1 loads ([128,256)) -- held in regs across steps 0-3
    f32x4 h0 = *(const f32x4*)(srcrow + 128);
    f32x4 h1 = *(const f32x4*)(srcrow + 132);
    f32x4 h2 = *(const f32x4*)(srcrow + 136);
    f32x4 h3 = *(const f32x4*)(srcrow + 140);

    // ---- fragment pointers ----
    const int m0 = wave * 64;                  // wave's m-slice base
    const uint4* aptr[4];
    const uint4* bptr[4];
#pragma unroll
    for (int mf = 0; mf < 4; ++mf)
        aptr[mf] = (const uint4*)&tokL[mf * 16 + lr][kg * 8];
#pragma unroll
    for (int nf = 0; nf < 4; ++nf) {
        int col = m0 + nf * 16 + lr;
        bptr[nf] = (const uint4*)(Wk + ((size_t)(b * D_MODEL + col)) * D_EMB + kg * 8);
    }

    f32x4 acc[4][4] = {};

    // ---- K-steps 0-3 (k < 128, only half-0 of tokL touched) ----
#pragma unroll
    for (int step = 0; step < 4; ++step) {
        bf16x8 af[4], bfr[4];
#pragma unroll
        for (int mf = 0; mf < 4; ++mf) {
            uint4 q = aptr[mf][step * 4];
            af[mf] = __builtin_bit_cast(bf16x8, q);
        }
#pragma unroll
        for (int nf = 0; nf < 4; ++nf) {
            uint4 q = bptr[nf][step * 4];
            bfr[nf] = __builtin_bit_cast(bf16x8, q);
        }
#pragma unroll
        for (int mf = 0; mf < 4; ++mf)
#pragma unroll
            for (int nf = 0; nf < 4; ++nf)
                acc[mf][nf] = __builtin_amdgcn_mfma_f32_16x16x32_bf16(
                    af[mf], bfr[nf], acc[mf][nf], 0, 0, 0);
    }

    // ---- land k-half 1 into LDS, then finish K ----
    *(bf16x8*)&tokL[srow][128 + sck]     = pack8(h0, h1);
    *(bf16x8*)&tokL[srow][128 + sck + 8] = pack8(h2, h3);
    __syncthreads();

#pragma unroll
    for (int step = 4; step < 8; ++step) {
        bf16x8 af[4], bfr[4];
#pragma unroll
        for (int mf = 0; mf < 4; ++mf) {
            uint4 q = aptr[mf][step * 4];
            af[mf] = __builtin_bit_cast(bf16x8, q);
        }
#pragma unroll
        for (int nf = 0; nf < 4; ++nf) {
            uint4 q = bptr[nf][step * 4];
            bfr[nf] = __builtin_bit_cast(bf16x8, q);
        }
#pragma unroll
        for (int mf = 0; mf < 4; ++mf)
#pragma unroll
            for (int nf = 0; nf < 4; ++nf)
                acc[mf][nf] = __builtin_amdgcn_mfma_f32_16x16x32_bf16(
                    af[mf], bfr[nf], acc[mf][nf], 0, 0, 0);
    }

    // ---- epilogue: bias, block-wide LN stats ----
    float bbv[4], gv[4], bv[4];
#pragma unroll
    for (int nf = 0; nf < 4; ++nf) {
        int col = m0 + nf * 16 + lr;
        bbv[nf] = bb[col];
        gv[nf]  = gamma[col];
        bv[nf]  = beta[col];
    }

#pragma unroll
    for (int mf = 0; mf < 4; ++mf) {
#pragma unroll
        for (int r = 0; r < 4; ++r) {
            float sum = 0.0f, sq = 0.0f;
#pragma unroll
            for (int nf = 0; nf < 4; ++nf) {
                float v = acc[mf][nf][r] + bbv[nf];
                acc[mf][nf][r] = v;
                sum += v;
                sq  += v * v;
            }
#pragma unroll
            for (int off = 1; off < 16; off <<= 1) {
                sum += __shfl_xor(sum, off);
                sq  += __shfl_xor(sq, off);
            }
            if (lr == 0) {
                int row = mf * 16 + kg * 4 + r;
                red_sum[wave][row] = sum;
                red_sq[wave][row]  = sq;
            }
        }
    }
    __syncthreads();

    if (t < TSB) {
        float s = 0.0f, q = 0.0f;
#pragma unroll
        for (int w = 0; w < 8; ++w) { s += red_sum[w][t]; q += red_sq[w][t]; }
        float mean = s * (1.0f / D_MODEL);
        float var  = q * (1.0f / D_MODEL) - mean * mean;
        stats[0][t] = mean;
        stats[1][t] = rsqrtf(var + LN_EPS);
    }
    __syncthreads();

    // ---- normalize + store ----
#pragma unroll
    for (int mf = 0; mf < 4; ++mf) {
#pragma unroll
        for (int r = 0; r < 4; ++r) {
            int row = mf * 16 + kg * 4 + r;
            float mean = stats[0][row];
            float rstd = stats[1][row];
            float* op = out + ((size_t)b * S + s0 + row) * D_MODEL + m0 + lr;
#pragma unroll
            for (int nf = 0; nf < 4; ++nf)
                op[nf * 16] = (acc[mf][nf][r] - mean) * rstd * gv[nf] + bv[nf];
        }
    }
}

// ---------------------------------------------------------------------------
extern "C" void kernel_launch(void* const* d_in, const int* in_sizes, int n_in,
                              void* d_out, int out_size, void* d_ws, size_t ws_size,
                              hipStream_t stream)
{
    const int*   seq          = (const int*)d_in[0];
    const int*   king_id      = (const int*)d_in[1];
    const float* token_tables = (const float*)d_in[2];
    const float* Wb           = (const float*)d_in[3];
    const float* bb           = (const float*)d_in[4];
    const float* king_table   = (const float*)d_in[5];
    const float* gamma        = (const float*)d_in[6];
    const float* beta         = (const float*)d_in[7];
    float* out = (float*)d_out;

    unsigned short* Wk = (unsigned short*)d_ws;   // B*D_MODEL*D_EMB bf16 = 4 MB

    wk_mfma<<<dim3((D_MODEL * D_EMB) / 256), dim3(256), 0, stream>>>(
        Wb, king_table, king_id, Wk);
    gemm_ln_mfma<<<dim3(S / TSB, B), dim3(512), 0, stream>>>(
        seq, king_id, token_tables, Wk, bb, gamma, beta, out);
}

// Round 11
// 59.340 us; speedup vs baseline: 1.5471x; 1.0111x over previous
//
#include <hip/hip_runtime.h>
#include <hip/hip_bf16.h>

#define B 16
#define S 2048
#define VOCAB 32000
#define D_EMB 256
#define D_MODEL 512
#define LN_EPS 1e-5f

using bf16x8 = __attribute__((ext_vector_type(8))) short;
using f32x4  = __attribute__((ext_vector_type(4))) float;

static __device__ __forceinline__ unsigned short f2bf(float f) {
    __hip_bfloat16 h = __float2bfloat16(f);   // RNE
    return *reinterpret_cast<unsigned short*>(&h);
}

static __device__ __forceinline__ bf16x8 pack8(f32x4 v0, f32x4 v1) {
    union { unsigned short us[8]; bf16x8 v; } pk;
    pk.us[0] = f2bf(v0.x); pk.us[1] = f2bf(v0.y);
    pk.us[2] = f2bf(v0.z); pk.us[3] = f2bf(v0.w);
    pk.us[4] = f2bf(v1.x); pk.us[5] = f2bf(v1.y);
    pk.us[6] = f2bf(v1.z); pk.us[7] = f2bf(v1.w);
    return pk.v;
}

// ---------------------------------------------------------------------------
// Kernel A (MFMA) — EXACT R5 form (measured: 23.1 µs ≈ its 21 µs Wb floor).
// ---------------------------------------------------------------------------
__global__ __launch_bounds__(256) void wk_mfma(
    const float* __restrict__ Wb,
    const float* __restrict__ king_table,
    const int* __restrict__ king_id,
    unsigned short* __restrict__ Wk)
{
    const int t    = threadIdx.x;
    const int lane = t & 63;
    const int wave = t >> 6;
    const int lr   = lane & 15;     // b index (B-frag col) / row index (A-frag)
    const int kg   = lane >> 4;     // k-group

    const int kid = king_id[lr];
    const float* kp = king_table + (size_t)kid * D_EMB + kg * 8;
    bf16x8 bemb[8];
#pragma unroll
    for (int step = 0; step < 8; ++step) {
        f32x4 v0 = *(const f32x4*)(kp + step * 32);
        f32x4 v1 = *(const f32x4*)(kp + step * 32 + 4);
        bemb[step] = pack8(v0, v1);
    }

    const int rbase = (blockIdx.x * 4 + wave) * 64;

#pragma unroll
    for (int mf = 0; mf < 4; ++mf) {
        const float* arow = Wb + (size_t)(rbase + mf * 16 + lr) * D_EMB + kg * 8;
        f32x4 acc = {};
#pragma unroll
        for (int step = 0; step < 8; ++step) {
            f32x4 v0 = *(const f32x4*)(arow + step * 32);
            f32x4 v1 = *(const f32x4*)(arow + step * 32 + 4);
            acc = __builtin_amdgcn_mfma_f32_16x16x32_bf16(
                pack8(v0, v1), bemb[step], acc, 0, 0, 0);
        }
        union { unsigned short us[4]; uint2 q; } st;
        st.us[0] = f2bf(acc[0]); st.us[1] = f2bf(acc[1]);
        st.us[2] = f2bf(acc[2]); st.us[3] = f2bf(acc[3]);
        *(uint2*)(Wk + (size_t)lr * (D_MODEL * D_EMB) + rbase + mf * 16 + kg * 4) = st.q;
    }
}

// ---------------------------------------------------------------------------
// Kernel B (MFMA) — R10 form + XCD-aware block decode:
// 1D grid 512, id = xcd + 8*k (HW round-robins linear id across 8 XCDs,
// m09). b = 2*xcd + (k>=32), tile = k&31  ->  each XCD owns exactly 2
// batches; its Wk working set = 2 x 256 KB = 512 KB, L2-resident (vs 4 MB
// thrash before). Exact load balance: 64 blocks/XCD = 2/CU, one round.
// Everything else byte-identical to the measured 60.0 µs R10 config.
// ---------------------------------------------------------------------------
#define TSB 64

__global__ __launch_bounds__(512, 4) void gemm_ln_mfma(
    const int* __restrict__ seq,
    const int* __restrict__ king_id,
    const float* __restrict__ token_tables,
    const unsigned short* __restrict__ Wk,
    const float* __restrict__ bb,
    const float* __restrict__ gamma,
    const float* __restrict__ beta,
    float* __restrict__ out)
{
    __shared__ unsigned short tokL[TSB][264];   // 64 x (256+8 pad) bf16 = 33 KB
    __shared__ float red_sum[8][TSB];
    __shared__ float red_sq[8][TSB];
    __shared__ float stats[2][TSB];             // [0]=mean, [1]=rstd

    // ---- XCD-aware decode: blocks with the same b pin to one XCD ----
    const int id   = blockIdx.x;
    const int xcd  = id & 7;
    const int k    = id >> 3;              // 0..63
    const int b    = xcd * 2 + (k >> 5);   // 2 batches per XCD
    const int tile = k & 31;

    const int s0   = tile * TSB;
    const int t    = threadIdx.x;
    const int lane = t & 63;
    const int wave = t >> 6;
    const int lr   = lane & 15;     // frag row/col index
    const int kg   = lane >> 4;     // k-group (0..3)

    const int kb = king_id[b];
    const float* ttab = token_tables + (size_t)kb * VOCAB * D_EMB;

    // staging geometry: thread t covers row = t>>3, k-chunk (t&7)*16 within
    // each 128-col half (16 floats = 4 dwordx4 per half).
    const int srow = t >> 3;
    const int sck  = (t & 7) * 16;
    const int tokidx = seq[b * S + s0 + srow];
    const float* srcrow = ttab + (size_t)tokidx * D_EMB + sck;

    // ---- phase 0: stage k-half 0 ([0,128)) ----
    {
        f32x4 v0 = *(const f32x4*)(srcrow + 0);
        f32x4 v1 = *(const f32x4*)(srcrow + 4);
        f32x4 v2 = *(const f32x4*)(srcrow + 8);
        f32x4 v3 = *(const f32x4*)(srcrow + 12);
        *(bf16x8*)&tokL[srow][sck]     = pack8(v0, v1);
        *(bf16x8*)&tokL[srow][sck + 8] = pack8(v2, v3);
    }
    __syncthreads();

    // ---- issue k-half 1 loads ([128,256)) -- held in regs across steps 0-3
    f32x4 h0 = *(const f32x4*)(srcrow + 128);
    f32x4 h1 = *(const f32x4*)(srcrow + 132);
    f32x4 h2 = *(const f32x4*)(srcrow + 136);
    f32x4 h3 = *(const f32x4*)(srcrow + 140);

    // ---- fragment pointers ----
    const int m0 = wave * 64;                  // wave's m-slice base
    const uint4* aptr[4];
    const uint4* bptr[4];
#pragma unroll
    for (int mf = 0; mf < 4; ++mf)
        aptr[mf] = (const uint4*)&tokL[mf * 16 + lr][kg * 8];
#pragma unroll
    for (int nf = 0; nf < 4; ++nf) {
        int col = m0 + nf * 16 + lr;
        bptr[nf] = (const uint4*)(Wk + ((size_t)(b * D_MODEL + col)) * D_EMB + kg * 8);
    }

    f32x4 acc[4][4] = {};

    // ---- K-steps 0-3 (k < 128, only half-0 of tokL touched) ----
#pragma unroll
    for (int step = 0; step < 4; ++step) {
        bf16x8 af[4], bfr[4];
#pragma unroll
        for (int mf = 0; mf < 4; ++mf) {
            uint4 q = aptr[mf][step * 4];
            af[mf] = __builtin_bit_cast(bf16x8, q);
        }
#pragma unroll
        for (int nf = 0; nf < 4; ++nf) {
            uint4 q = bptr[nf][step * 4];
            bfr[nf] = __builtin_bit_cast(bf16x8, q);
        }
#pragma unroll
        for (int mf = 0; mf < 4; ++mf)
#pragma unroll
            for (int nf = 0; nf < 4; ++nf)
                acc[mf][nf] = __builtin_amdgcn_mfma_f32_16x16x32_bf16(
                    af[mf], bfr[nf], acc[mf][nf], 0, 0, 0);
    }

    // ---- land k-half 1 into LDS, then finish K ----
    *(bf16x8*)&tokL[srow][128 + sck]     = pack8(h0, h1);
    *(bf16x8*)&tokL[srow][128 + sck + 8] = pack8(h2, h3);
    __syncthreads();

#pragma unroll
    for (int step = 4; step < 8; ++step) {
        bf16x8 af[4], bfr[4];
#pragma unroll
        for (int mf = 0; mf < 4; ++mf) {
            uint4 q = aptr[mf][step * 4];
            af[mf] = __builtin_bit_cast(bf16x8, q);
        }
#pragma unroll
        for (int nf = 0; nf < 4; ++nf) {
            uint4 q = bptr[nf][step * 4];
            bfr[nf] = __builtin_bit_cast(bf16x8, q);
        }
#pragma unroll
        for (int mf = 0; mf < 4; ++mf)
#pragma unroll
            for (int nf = 0; nf < 4; ++nf)
                acc[mf][nf] = __builtin_amdgcn_mfma_f32_16x16x32_bf16(
                    af[mf], bfr[nf], acc[mf][nf], 0, 0, 0);
    }

    // ---- epilogue: bias, block-wide LN stats ----
    float bbv[4], gv[4], bv[4];
#pragma unroll
    for (int nf = 0; nf < 4; ++nf) {
        int col = m0 + nf * 16 + lr;
        bbv[nf] = bb[col];
        gv[nf]  = gamma[col];
        bv[nf]  = beta[col];
    }

#pragma unroll
    for (int mf = 0; mf < 4; ++mf) {
#pragma unroll
        for (int r = 0; r < 4; ++r) {
            float sum = 0.0f, sq = 0.0f;
#pragma unroll
            for (int nf = 0; nf < 4; ++nf) {
                float v = acc[mf][nf][r] + bbv[nf];
                acc[mf][nf][r] = v;
                sum += v;
                sq  += v * v;
            }
#pragma unroll
            for (int off = 1; off < 16; off <<= 1) {
                sum += __shfl_xor(sum, off);
                sq  += __shfl_xor(sq, off);
            }
            if (lr == 0) {
                int row = mf * 16 + kg * 4 + r;
                red_sum[wave][row] = sum;
                red_sq[wave][row]  = sq;
            }
        }
    }
    __syncthreads();

    if (t < TSB) {
        float s = 0.0f, q = 0.0f;
#pragma unroll
        for (int w = 0; w < 8; ++w) { s += red_sum[w][t]; q += red_sq[w][t]; }
        float mean = s * (1.0f / D_MODEL);
        float var  = q * (1.0f / D_MODEL) - mean * mean;
        stats[0][t] = mean;
        stats[1][t] = rsqrtf(var + LN_EPS);
    }
    __syncthreads();

    // ---- normalize + store ----
#pragma unroll
    for (int mf = 0; mf < 4; ++mf) {
#pragma unroll
        for (int r = 0; r < 4; ++r) {
            int row = mf * 16 + kg * 4 + r;
            float mean = stats[0][row];
            float rstd = stats[1][row];
            float* op = out + ((size_t)b * S + s0 + row) * D_MODEL + m0 + lr;
#pragma unroll
            for (int nf = 0; nf < 4; ++nf)
                op[nf * 16] = (acc[mf][nf][r] - mean) * rstd * gv[nf] + bv[nf];
        }
    }
}

// ---------------------------------------------------------------------------
extern "C" void kernel_launch(void* const* d_in, const int* in_sizes, int n_in,
                              void* d_out, int out_size, void* d_ws, size_t ws_size,
                              hipStream_t stream)
{
    const int*   seq          = (const int*)d_in[0];
    const int*   king_id      = (const int*)d_in[1];
    const float* token_tables = (const float*)d_in[2];
    const float* Wb           = (const float*)d_in[3];
    const float* bb           = (const float*)d_in[4];
    const float* king_table   = (const float*)d_in[5];
    const float* gamma        = (const float*)d_in[6];
    const float* beta         = (const float*)d_in[7];
    float* out = (float*)d_out;

    unsigned short* Wk = (unsigned short*)d_ws;   // B*D_MODEL*D_EMB bf16 = 4 MB

    wk_mfma<<<dim3((D_MODEL * D_EMB) / 256), dim3(256), 0, stream>>>(
        Wb, king_table, king_id, Wk);
    gemm_ln_mfma<<<dim3(S / TSB * B), dim3(512), 0, stream>>>(
        seq, king_id, token_tables, Wk, bb, gamma, beta, out);
}